// Round 4
// baseline (583.787 us; speedup 1.0000x reference)
//
#include <hip/hip_runtime.h>

#define K_CODES 1024
#define DIMS    256
#define NROWS   32768   // B*H*W = 32*32*32

// ---------------- new-path geometry ----------------
#define NGROUPS       16     // code groups of 64 (one per wave-lane set)
#define ROWS_PER_WAVE 64     // halved vs round 3 -> 8192 waves -> 8/SIMD target
#define RP            16     // rows per pass (held in acc regs)

// ws layout (float units)
#define WS_ET    0
#define WS_ESQ   (WS_ET  + DIMS * K_CODES)        // 262144
#define WS_XSQ   (WS_ESQ + K_CODES)               // +1024
#define WS_CAND  (WS_XSQ + NROWS)                 // +32768
#define WS_NEED_FLOATS (WS_CAND + NGROUPS * NROWS * 2)
#define WS_NEED_BYTES  ((size_t)WS_NEED_FLOATS * 4)

// ---------------------------------------------------------------------------
// numpy-bitwise sum of squares of a 256-element row (verified round 2).
// ---------------------------------------------------------------------------
__device__ __forceinline__ float sq_at(const float* p, int d, int stride) {
#pragma clang fp contract(off)
    const float v = p[(size_t)d * stride];
    return v * v;
}

__device__ __forceinline__ float np_block_sq(const float* p, int stride, int o, int n) {
#pragma clang fp contract(off)
    float r[8];
    #pragma unroll
    for (int k = 0; k < 8; ++k) r[k] = sq_at(p, o + k, stride);
    const int n8 = n - (n % 8);
    for (int i = 8; i < n8; i += 8) {
        #pragma unroll
        for (int k = 0; k < 8; ++k) r[k] = r[k] + sq_at(p, o + i + k, stride);
    }
    float res = ((r[0] + r[1]) + (r[2] + r[3])) + ((r[4] + r[5]) + (r[6] + r[7]));
    for (int i = n8; i < n; ++i) res = res + sq_at(p, o + i, stride);
    return res;
}

__device__ __forceinline__ float np_sumsq_row(const float* p, int stride) {
#pragma clang fp contract(off)
    const float p120 = np_block_sq(p, stride, 1,   120);
    const float p64  = np_block_sq(p, stride, 121, 64);
    const float p71  = np_block_sq(p, stride, 185, 71);
    const float s135 = p64 + p71;
    const float s255 = p120 + s135;
    return sq_at(p, 0, stride) + s255;
}

// ---------------- x_sq ------------------------------------------------------
__global__ void vq_xsq_kernel(const float* __restrict__ x, float* __restrict__ xsq) {
    const int n = blockIdx.x * 256 + threadIdx.x;
    const float* p = x + ((size_t)(n >> 10)) * (DIMS * 1024) + (n & 1023);
    xsq[n] = np_sumsq_row(p, 1024);
}

// ---------------- e_sq ------------------------------------------------------
__global__ void vq_esq_kernel(const float* __restrict__ cb, float* __restrict__ esq) {
    const int c = blockIdx.x * 256 + threadIdx.x;
    esq[c] = np_sumsq_row(cb + (size_t)c * DIMS, 1);
}

// ---------------- codebook transpose: e_t[d][c] = cb[c][d] ------------------
__global__ void vq_tr_kernel(const float* __restrict__ cb, float* __restrict__ et) {
    __shared__ float tile[32][33];
    const int tx = threadIdx.x & 31;
    const int ty = threadIdx.x >> 5;               // 0..7
    const int c0 = (blockIdx.x & 31) * 32;         // 32 code tiles
    const int d0 = (blockIdx.x >> 5) * 32;         // 8 dim tiles
    #pragma unroll
    for (int i = 0; i < 4; ++i) {
        const int cl = ty + i * 8;
        tile[cl][tx] = cb[(size_t)(c0 + cl) * DIMS + d0 + tx];
    }
    __syncthreads();
    #pragma unroll
    for (int i = 0; i < 4; ++i) {
        const int dl = ty + i * 8;
        et[(size_t)(d0 + dl) * K_CODES + c0 + tx] = tile[tx][dl];
    }
}

// ---------------- main: lane = code, x via wave-uniform scalar loads --------
__global__ __launch_bounds__(256, 8)
void vq_main2_kernel(const float* __restrict__ x, const float* __restrict__ et,
                     const float* __restrict__ esq, const float* __restrict__ xsq,
                     float2* __restrict__ cand) {
    const int wid  = __builtin_amdgcn_readfirstlane((int)(threadIdx.x >> 6));
    const int lane = threadIdx.x & 63;
    const int W     = blockIdx.x * 4 + wid;        // 0..8191
    const int g     = W & (NGROUPS - 1);           // code group
    const int slice = W >> 4;                      // 0..511 row slice
    const int c     = g * 64 + lane;               // this lane's code
    const int row_base = slice * ROWS_PER_WAVE;    // 64 | 1024 -> one image
    const int b    = row_base >> 10;
    const int hw0  = row_base & 1023;
    const float* xb  = x + (size_t)b * (DIMS * 1024) + hw0;  // + d*1024 + r
    const float* etc = et + c;                     // + d*1024
    const float esq_c = esq[c];

    for (int rp = 0; rp < ROWS_PER_WAVE / RP; ++rp) {
        const int r0 = rp * RP;

        float acc[RP];
        #pragma unroll
        for (int r = 0; r < RP; ++r) acc[r] = 0.0f;

        // e double-buffer: 4 dims/chunk, coalesced dword loads from e_t
        float en[4];
        #pragma unroll
        for (int d = 0; d < 4; ++d) en[d] = etc[(size_t)d * K_CODES];

        // unroll 4: renames per-chunk x/e regs so the scheduler can hoist
        // chunks n+1..n+3's s_load/VMEM above chunk n's FMA block (ILP).
        #pragma unroll 4
        for (int dk = 0; dk < DIMS / 4; ++dk) {
            float ec[4];
            #pragma unroll
            for (int d = 0; d < 4; ++d) ec[d] = en[d];
            if (dk < DIMS / 4 - 1) {
                #pragma unroll
                for (int d = 0; d < 4; ++d)
                    en[d] = etc[(size_t)((dk + 1) * 4 + d) * K_CODES];
            }
            // per dim: 16 wave-uniform x loads (contiguous 64B -> s_load_dwordx16),
            // then 16 FMAs; d ascending outer keeps each acc's fma order = np/BLAS.
            #pragma unroll
            for (int d = 0; d < 4; ++d) {
                float xv[RP];
                #pragma unroll
                for (int r = 0; r < RP; ++r)
                    xv[r] = xb[(size_t)(dk * 4 + d) * 1024 + r0 + r];
                #pragma unroll
                for (int r = 0; r < RP; ++r)
                    acc[r] = fmaf(xv[r], ec[d], acc[r]);
            }
        }

        // epilogue: exact np op order, then exact first-index argmin within wave
        {
#pragma clang fp contract(off)
            float keepv = 0.0f; int keepc = 0;
            #pragma unroll
            for (int r = 0; r < RP; ++r) {
                const float xs_r = xsq[row_base + r0 + r];      // uniform
                const float t3 = xs_r - 2.0f * acc[r];
                float bv = t3 + esq_c;
                int   bc = c;
                #pragma unroll
                for (int off = 1; off < 64; off <<= 1) {
                    const float ov = __shfl_xor(bv, off, 64);
                    const int   oc = __shfl_xor(bc, off, 64);
                    if (ov < bv || (ov == bv && oc < bc)) { bv = ov; bc = oc; }
                }
                if (lane == r) { keepv = bv; keepc = bc; }      // lane r keeps row r
            }
            if (lane < RP) {
                cand[(size_t)g * NROWS + row_base + r0 + lane] =
                    make_float2(keepv, __int_as_float(keepc));
            }
        }
    }
}

// ---------------- cross-group lexmin reduce ---------------------------------
__global__ void vq_reduce_kernel(const float2* __restrict__ cand, int* __restrict__ out) {
    const int row = blockIdx.x * 256 + threadIdx.x;
    float2 p = cand[row];
    float bv = p.x; int bc = __float_as_int(p.y);
    #pragma unroll
    for (int gg = 1; gg < NGROUPS; ++gg) {
        const float2 q = cand[(size_t)gg * NROWS + row];
        const float v = q.x; const int qc = __float_as_int(q.y);
        if (v < bv || (v == bv && qc < bc)) { bv = v; bc = qc; }
    }
    out[row] = bc;
}

// ===========================================================================
// Fallback path (round-2 kernel, verified passing) — used if ws too small.
// ===========================================================================
#define BM      64
#define BN      128
#define DK      32
#define PITCH   36

__global__ __launch_bounds__(256, 2)
void vq_main_kernel(const float* __restrict__ x, const float* __restrict__ cb,
                    const float* __restrict__ esq, const float* __restrict__ xsq,
                     int* __restrict__ out) {
    __shared__ float xs[BM * PITCH];

    const int t   = threadIdx.x;
    const int tc  = t & 15;
    const int tr  = t >> 4;
    const int row0 = blockIdx.x * BM;
    const int b   = row0 >> 10;
    const int hw0 = row0 & 1023;
    const float* xb = x + (size_t)b * DIMS * 1024 + hw0;

    float xsqr[4];
    #pragma unroll
    for (int i = 0; i < 4; ++i) xsqr[i] = xsq[row0 + tr * 4 + i];

    float bestv[4];
    int   bestc[4];
    #pragma unroll
    for (int i = 0; i < 4; ++i) { bestv[i] = 3.4e38f; bestc[i] = 0; }

    for (int cc = 0; cc < K_CODES / BN; ++cc) {
        const float* ep[8];
        #pragma unroll
        for (int j = 0; j < 8; ++j)
            ep[j] = cb + (size_t)(cc * BN + tc + 16 * j) * DIMS;

        float acc[4][8];
        #pragma unroll
        for (int i = 0; i < 4; ++i)
            #pragma unroll
            for (int j = 0; j < 8; ++j) acc[i][j] = 0.0f;

        for (int dk = 0; dk < DIMS / DK; ++dk) {
            __syncthreads();
            #pragma unroll
            for (int ii = 0; ii < 2; ++ii) {
                const int li = t + 256 * ii;
                const int d  = (li >> 2) & 31;
                const int h4 = (li & 3) | ((li >> 7) << 2);
                const float4 v = *reinterpret_cast<const float4*>(
                    xb + (size_t)(dk * DK + d) * 1024 + h4 * 4);
                xs[(h4 * 4 + 0) * PITCH + d] = v.x;
                xs[(h4 * 4 + 1) * PITCH + d] = v.y;
                xs[(h4 * 4 + 2) * PITCH + d] = v.z;
                xs[(h4 * 4 + 3) * PITCH + d] = v.w;
            }
            __syncthreads();

            #pragma unroll
            for (int d4 = 0; d4 < DK; d4 += 4) {
                float4 xv[4];
                #pragma unroll
                for (int i = 0; i < 4; ++i)
                    xv[i] = *reinterpret_cast<const float4*>(&xs[(tr * 4 + i) * PITCH + d4]);
                float4 ev[8];
                #pragma unroll
                for (int j = 0; j < 8; ++j)
                    ev[j] = *reinterpret_cast<const float4*>(ep[j] + dk * DK + d4);
                #pragma unroll
                for (int i = 0; i < 4; ++i) {
                    #pragma unroll
                    for (int j = 0; j < 8; ++j) {
                        acc[i][j] = fmaf(xv[i].x, ev[j].x, acc[i][j]);
                        acc[i][j] = fmaf(xv[i].y, ev[j].y, acc[i][j]);
                        acc[i][j] = fmaf(xv[i].z, ev[j].z, acc[i][j]);
                        acc[i][j] = fmaf(xv[i].w, ev[j].w, acc[i][j]);
                    }
                }
            }
        }

        {
#pragma clang fp contract(off)
            #pragma unroll
            for (int j = 0; j < 8; ++j) {
                const int c = cc * BN + tc + 16 * j;
                const float es = esq[c];
                #pragma unroll
                for (int i = 0; i < 4; ++i) {
                    const float t3 = xsqr[i] - 2.0f * acc[i][j];
                    const float v  = t3 + es;
                    if (v < bestv[i]) { bestv[i] = v; bestc[i] = c; }
                }
            }
        }
    }

    __syncthreads();
    float* rv = xs;
    int*   rc = reinterpret_cast<int*>(xs + BM * 16);
    #pragma unroll
    for (int i = 0; i < 4; ++i) {
        const int r = tr * 4 + i;
        rv[r * 16 + tc] = bestv[i];
        rc[r * 16 + tc] = bestc[i];
    }
    __syncthreads();
    if (t < BM) {
        float bv = rv[t * 16];
        int   bc = rc[t * 16];
        #pragma unroll
        for (int k = 1; k < 16; ++k) {
            const float v = rv[t * 16 + k];
            const int   cidx = rc[t * 16 + k];
            if (v < bv || (v == bv && cidx < bc)) { bv = v; bc = cidx; }
        }
        out[row0 + t] = bc;
    }
}

// ===========================================================================
extern "C" void kernel_launch(void* const* d_in, const int* in_sizes, int n_in,
                              void* d_out, int out_size, void* d_ws, size_t ws_size,
                              hipStream_t stream) {
    const float* x  = (const float*)d_in[0];   // [32, 256, 32, 32]
    const float* cb = (const float*)d_in[1];   // [1024, 256]
    int* out = (int*)d_out;                    // [32768] int32
    float* ws = (float*)d_ws;

    if (ws_size >= WS_NEED_BYTES) {
        float*  et   = ws + WS_ET;
        float*  esq  = ws + WS_ESQ;
        float*  xsq  = ws + WS_XSQ;
        float2* cand = (float2*)(ws + WS_CAND);

        vq_xsq_kernel<<<NROWS / 256, 256, 0, stream>>>(x, xsq);
        vq_esq_kernel<<<K_CODES / 256, 256, 0, stream>>>(cb, esq);
        vq_tr_kernel<<<256, 256, 0, stream>>>(cb, et);
        vq_main2_kernel<<<(NROWS / ROWS_PER_WAVE) * NGROUPS / 4, 256, 0, stream>>>(
            x, et, esq, xsq, cand);
        vq_reduce_kernel<<<NROWS / 256, 256, 0, stream>>>(cand, out);
    } else {
        float* esq = ws;
        float* xsq = ws + K_CODES;
        vq_xsq_kernel<<<NROWS / 256, 256, 0, stream>>>(x, xsq);
        vq_esq_kernel<<<K_CODES / 256, 256, 0, stream>>>(cb, esq);
        vq_main_kernel<<<NROWS / BM, 256, 0, stream>>>(x, cb, esq, xsq, out);
    }
}

// Round 5
// 383.464 us; speedup vs baseline: 1.5224x; 1.5224x over previous
//
#include <hip/hip_runtime.h>

#define K_CODES 1024
#define DIMS    256
#define NROWS   32768   // B*H*W = 32*32*32

// ---------------- new-path geometry ----------------
#define NGROUPS       16     // code groups of 64 (one per wave-lane set)
#define ROWS_PER_WAVE 64     // 8192 waves -> 8/SIMD target
#define RP            16     // rows per pass (held in acc regs)

// ws layout (float units)
#define WS_ET    0
#define WS_ESQ   (WS_ET  + DIMS * K_CODES)        // 262144
#define WS_XSQ   (WS_ESQ + K_CODES)               // +1024
#define WS_CAND  (WS_XSQ + NROWS)                 // +32768
#define WS_NEED_FLOATS (WS_CAND + NGROUPS * NROWS * 2)
#define WS_NEED_BYTES  ((size_t)WS_NEED_FLOATS * 4)

// ---------------------------------------------------------------------------
// numpy-bitwise sum of squares of a 256-element row (verified round 2).
// ---------------------------------------------------------------------------
__device__ __forceinline__ float sq_at(const float* p, int d, int stride) {
#pragma clang fp contract(off)
    const float v = p[(size_t)d * stride];
    return v * v;
}

__device__ __forceinline__ float np_block_sq(const float* p, int stride, int o, int n) {
#pragma clang fp contract(off)
    float r[8];
    #pragma unroll
    for (int k = 0; k < 8; ++k) r[k] = sq_at(p, o + k, stride);
    const int n8 = n - (n % 8);
    for (int i = 8; i < n8; i += 8) {
        #pragma unroll
        for (int k = 0; k < 8; ++k) r[k] = r[k] + sq_at(p, o + i + k, stride);
    }
    float res = ((r[0] + r[1]) + (r[2] + r[3])) + ((r[4] + r[5]) + (r[6] + r[7]));
    for (int i = n8; i < n; ++i) res = res + sq_at(p, o + i, stride);
    return res;
}

__device__ __forceinline__ float np_sumsq_row(const float* p, int stride) {
#pragma clang fp contract(off)
    const float p120 = np_block_sq(p, stride, 1,   120);
    const float p64  = np_block_sq(p, stride, 121, 64);
    const float p71  = np_block_sq(p, stride, 185, 71);
    const float s135 = p64 + p71;
    const float s255 = p120 + s135;
    return sq_at(p, 0, stride) + s255;
}

// ---------------- x_sq ------------------------------------------------------
__global__ void vq_xsq_kernel(const float* __restrict__ x, float* __restrict__ xsq) {
    const int n = blockIdx.x * 256 + threadIdx.x;
    const float* p = x + ((size_t)(n >> 10)) * (DIMS * 1024) + (n & 1023);
    xsq[n] = np_sumsq_row(p, 1024);
}

// ---------------- e_sq ------------------------------------------------------
__global__ void vq_esq_kernel(const float* __restrict__ cb, float* __restrict__ esq) {
    const int c = blockIdx.x * 256 + threadIdx.x;
    esq[c] = np_sumsq_row(cb + (size_t)c * DIMS, 1);
}

// ---------------- codebook transpose: e_t[d][c] = cb[c][d] ------------------
__global__ void vq_tr_kernel(const float* __restrict__ cb, float* __restrict__ et) {
    __shared__ float tile[32][33];
    const int tx = threadIdx.x & 31;
    const int ty = threadIdx.x >> 5;               // 0..7
    const int c0 = (blockIdx.x & 31) * 32;         // 32 code tiles
    const int d0 = (blockIdx.x >> 5) * 32;         // 8 dim tiles
    #pragma unroll
    for (int i = 0; i < 4; ++i) {
        const int cl = ty + i * 8;
        tile[cl][tx] = cb[(size_t)(c0 + cl) * DIMS + d0 + tx];
    }
    __syncthreads();
    #pragma unroll
    for (int i = 0; i < 4; ++i) {
        const int dl = ty + i * 8;
        et[(size_t)(d0 + dl) * K_CODES + c0 + tx] = tile[tx][dl];
    }
}

// ---------------- main: lane = code, x via wave-uniform scalar loads --------
// Loop body kept EXACTLY as round 3 (which compiled to s_load_dwordx16 x-loads,
// SGPR=112): no outer unroll — round 4 showed unroll-4 blows the SGPR budget
// and demotes x-loads to per-lane VALU loads (2.3x VALU issue time).
__global__ __launch_bounds__(256, 8)
void vq_main2_kernel(const float* __restrict__ x, const float* __restrict__ et,
                     const float* __restrict__ esq, const float* __restrict__ xsq,
                     float2* __restrict__ cand) {
    const int wid  = __builtin_amdgcn_readfirstlane((int)(threadIdx.x >> 6));
    const int lane = threadIdx.x & 63;
    const int W     = blockIdx.x * 4 + wid;        // 0..8191
    const int g     = W & (NGROUPS - 1);           // code group
    const int slice = W >> 4;                      // 0..511 row slice
    const int c     = g * 64 + lane;               // this lane's code
    const int row_base = slice * ROWS_PER_WAVE;    // 64 | 1024 -> one image
    const int b    = row_base >> 10;
    const int hw0  = row_base & 1023;
    const float* xb  = x + (size_t)b * (DIMS * 1024) + hw0;  // + d*1024 + r
    const float* etc = et + c;                     // + d*1024
    const float esq_c = esq[c];

    for (int rp = 0; rp < ROWS_PER_WAVE / RP; ++rp) {
        const int r0 = rp * RP;

        float acc[RP];
        #pragma unroll
        for (int r = 0; r < RP; ++r) acc[r] = 0.0f;

        // e double-buffer: 4 dims/chunk, coalesced dword loads from e_t
        float en[4];
        #pragma unroll
        for (int d = 0; d < 4; ++d) en[d] = etc[(size_t)d * K_CODES];

        for (int dk = 0; dk < DIMS / 4; ++dk) {
            float ec[4];
            #pragma unroll
            for (int d = 0; d < 4; ++d) ec[d] = en[d];
            if (dk < DIMS / 4 - 1) {
                #pragma unroll
                for (int d = 0; d < 4; ++d)
                    en[d] = etc[(size_t)((dk + 1) * 4 + d) * K_CODES];
            }
            // per dim: 16 wave-uniform x loads (contiguous 64B -> s_load_dwordx16),
            // then 16 FMAs; d ascending outer keeps each acc's fma order = np/BLAS.
            #pragma unroll
            for (int d = 0; d < 4; ++d) {
                float xv[RP];
                #pragma unroll
                for (int r = 0; r < RP; ++r)
                    xv[r] = xb[(size_t)(dk * 4 + d) * 1024 + r0 + r];
                #pragma unroll
                for (int r = 0; r < RP; ++r)
                    acc[r] = fmaf(xv[r], ec[d], acc[r]);
            }
        }

        // epilogue: exact np op order, then exact first-index argmin within wave
        {
#pragma clang fp contract(off)
            float keepv = 0.0f; int keepc = 0;
            #pragma unroll
            for (int r = 0; r < RP; ++r) {
                const float xs_r = xsq[row_base + r0 + r];      // uniform
                const float t3 = xs_r - 2.0f * acc[r];
                float bv = t3 + esq_c;
                int   bc = c;
                #pragma unroll
                for (int off = 1; off < 64; off <<= 1) {
                    const float ov = __shfl_xor(bv, off, 64);
                    const int   oc = __shfl_xor(bc, off, 64);
                    if (ov < bv || (ov == bv && oc < bc)) { bv = ov; bc = oc; }
                }
                if (lane == r) { keepv = bv; keepc = bc; }      // lane r keeps row r
            }
            if (lane < RP) {
                cand[(size_t)g * NROWS + row_base + r0 + lane] =
                    make_float2(keepv, __int_as_float(keepc));
            }
        }
    }
}

// ---------------- cross-group lexmin reduce ---------------------------------
__global__ void vq_reduce_kernel(const float2* __restrict__ cand, int* __restrict__ out) {
    const int row = blockIdx.x * 256 + threadIdx.x;
    float2 p = cand[row];
    float bv = p.x; int bc = __float_as_int(p.y);
    #pragma unroll
    for (int gg = 1; gg < NGROUPS; ++gg) {
        const float2 q = cand[(size_t)gg * NROWS + row];
        const float v = q.x; const int qc = __float_as_int(q.y);
        if (v < bv || (v == bv && qc < bc)) { bv = v; bc = qc; }
    }
    out[row] = bc;
}

// ===========================================================================
// Fallback path (round-2 kernel, verified passing) — used if ws too small.
// ===========================================================================
#define BM      64
#define BN      128
#define DK      32
#define PITCH   36

__global__ __launch_bounds__(256, 2)
void vq_main_kernel(const float* __restrict__ x, const float* __restrict__ cb,
                    const float* __restrict__ esq, const float* __restrict__ xsq,
                    int* __restrict__ out) {
    __shared__ float xs[BM * PITCH];

    const int t   = threadIdx.x;
    const int tc  = t & 15;
    const int tr  = t >> 4;
    const int row0 = blockIdx.x * BM;
    const int b   = row0 >> 10;
    const int hw0 = row0 & 1023;
    const float* xb = x + (size_t)b * DIMS * 1024 + hw0;

    float xsqr[4];
    #pragma unroll
    for (int i = 0; i < 4; ++i) xsqr[i] = xsq[row0 + tr * 4 + i];

    float bestv[4];
    int   bestc[4];
    #pragma unroll
    for (int i = 0; i < 4; ++i) { bestv[i] = 3.4e38f; bestc[i] = 0; }

    for (int cc = 0; cc < K_CODES / BN; ++cc) {
        const float* ep[8];
        #pragma unroll
        for (int j = 0; j < 8; ++j)
            ep[j] = cb + (size_t)(cc * BN + tc + 16 * j) * DIMS;

        float acc[4][8];
        #pragma unroll
        for (int i = 0; i < 4; ++i)
            #pragma unroll
            for (int j = 0; j < 8; ++j) acc[i][j] = 0.0f;

        for (int dk = 0; dk < DIMS / DK; ++dk) {
            __syncthreads();
            #pragma unroll
            for (int ii = 0; ii < 2; ++ii) {
                const int li = t + 256 * ii;
                const int d  = (li >> 2) & 31;
                const int h4 = (li & 3) | ((li >> 7) << 2);
                const float4 v = *reinterpret_cast<const float4*>(
                    xb + (size_t)(dk * DK + d) * 1024 + h4 * 4);
                xs[(h4 * 4 + 0) * PITCH + d] = v.x;
                xs[(h4 * 4 + 1) * PITCH + d] = v.y;
                xs[(h4 * 4 + 2) * PITCH + d] = v.z;
                xs[(h4 * 4 + 3) * PITCH + d] = v.w;
            }
            __syncthreads();

            #pragma unroll
            for (int d4 = 0; d4 < DK; d4 += 4) {
                float4 xv[4];
                #pragma unroll
                for (int i = 0; i < 4; ++i)
                    xv[i] = *reinterpret_cast<const float4*>(&xs[(tr * 4 + i) * PITCH + d4]);
                float4 ev[8];
                #pragma unroll
                for (int j = 0; j < 8; ++j)
                    ev[j] = *reinterpret_cast<const float4*>(ep[j] + dk * DK + d4);
                #pragma unroll
                for (int i = 0; i < 4; ++i) {
                    #pragma unroll
                    for (int j = 0; j < 8; ++j) {
                        acc[i][j] = fmaf(xv[i].x, ev[j].x, acc[i][j]);
                        acc[i][j] = fmaf(xv[i].y, ev[j].y, acc[i][j]);
                        acc[i][j] = fmaf(xv[i].z, ev[j].z, acc[i][j]);
                        acc[i][j] = fmaf(xv[i].w, ev[j].w, acc[i][j]);
                    }
                }
            }
        }

        {
#pragma clang fp contract(off)
            #pragma unroll
            for (int j = 0; j < 8; ++j) {
                const int c = cc * BN + tc + 16 * j;
                const float es = esq[c];
                #pragma unroll
                for (int i = 0; i < 4; ++i) {
                    const float t3 = xsqr[i] - 2.0f * acc[i][j];
                    const float v  = t3 + es;
                    if (v < bestv[i]) { bestv[i] = v; bestc[i] = c; }
                }
            }
        }
    }

    __syncthreads();
    float* rv = xs;
    int*   rc = reinterpret_cast<int*>(xs + BM * 16);
    #pragma unroll
    for (int i = 0; i < 4; ++i) {
        const int r = tr * 4 + i;
        rv[r * 16 + tc] = bestv[i];
        rc[r * 16 + tc] = bestc[i];
    }
    __syncthreads();
    if (t < BM) {
        float bv = rv[t * 16];
        int   bc = rc[t * 16];
        #pragma unroll
        for (int k = 1; k < 16; ++k) {
            const float v = rv[t * 16 + k];
            const int   cidx = rc[t * 16 + k];
            if (v < bv || (v == bv && cidx < bc)) { bv = v; bc = cidx; }
        }
        out[row0 + t] = bc;
    }
}

// ===========================================================================
extern "C" void kernel_launch(void* const* d_in, const int* in_sizes, int n_in,
                              void* d_out, int out_size, void* d_ws, size_t ws_size,
                              hipStream_t stream) {
    const float* x  = (const float*)d_in[0];   // [32, 256, 32, 32]
    const float* cb = (const float*)d_in[1];   // [1024, 256]
    int* out = (int*)d_out;                    // [32768] int32
    float* ws = (float*)d_ws;

    if (ws_size >= WS_NEED_BYTES) {
        float*  et   = ws + WS_ET;
        float*  esq  = ws + WS_ESQ;
        float*  xsq  = ws + WS_XSQ;
        float2* cand = (float2*)(ws + WS_CAND);

        vq_xsq_kernel<<<NROWS / 256, 256, 0, stream>>>(x, xsq);
        vq_esq_kernel<<<K_CODES / 256, 256, 0, stream>>>(cb, esq);
        vq_tr_kernel<<<256, 256, 0, stream>>>(cb, et);
        vq_main2_kernel<<<(NROWS / ROWS_PER_WAVE) * NGROUPS / 4, 256, 0, stream>>>(
            x, et, esq, xsq, cand);
        vq_reduce_kernel<<<NROWS / 256, 256, 0, stream>>>(cand, out);
    } else {
        float* esq = ws;
        float* xsq = ws + K_CODES;
        vq_xsq_kernel<<<NROWS / 256, 256, 0, stream>>>(x, xsq);
        vq_esq_kernel<<<K_CODES / 256, 256, 0, stream>>>(cb, esq);
        vq_main_kernel<<<NROWS / BM, 256, 0, stream>>>(x, cb, esq, xsq, out);
    }
}